// Round 2
// baseline (270.761 us; speedup 1.0000x reference)
//
#include <hip/hip_runtime.h>
#include <math.h>

#define NQ   512
#define DD   27
#define NC   10
#define KK   3
#define FC   128
#define FCD  (FC*DD)     // 3456
#define NTHR 256

static __device__ __forceinline__ unsigned fbits(float x){ return __float_as_uint(x); }

// K1: scale[d] = max |features[:,d]|.  Lane-residue trick: with total threads and
// stride both ≡ 0 (mod 27), each float4 component's dim index is constant per lane.
__global__ void k_scale(const float* __restrict__ feats, unsigned* __restrict__ scale_bits,
                        int total, int total_f4) {
  __shared__ unsigned smax[DD];
  int t = threadIdx.x;
  if (t < DD) smax[t] = 0u;
  __syncthreads();
  int gid = blockIdx.x * blockDim.x + t;
  int stride = gridDim.x * blockDim.x;       // 432*256 = 110592 = 27*4096
  const float4* f4 = (const float4*)feats;
  float m0=0.f, m1=0.f, m2=0.f, m3=0.f;
  for (int i = gid; i < total_f4; i += stride) {
    float4 v = f4[i];
    m0 = fmaxf(m0, fabsf(v.x));
    m1 = fmaxf(m1, fabsf(v.y));
    m2 = fmaxf(m2, fabsf(v.z));
    m3 = fmaxf(m3, fabsf(v.w));
  }
  int d0 = (4*gid) % DD;
  atomicMax(&smax[d0],          fbits(m0));
  atomicMax(&smax[(d0+1)%DD],   fbits(m1));
  atomicMax(&smax[(d0+2)%DD],   fbits(m2));
  atomicMax(&smax[(d0+3)%DD],   fbits(m3));
  if (gid == 0) {  // generic tail (not hit for 5.4M floats, exact /4)
    for (int i = total_f4*4; i < total; ++i)
      atomicMax(&scale_bits[i % DD], fbits(fabsf(feats[i])));
  }
  __syncthreads();
  if (t < DD) atomicMax(&scale_bits[t], smax[t]);
}

// K2: rscale = divide_no_nan-style reciprocal; scaled queries + qnorm.
__global__ void k_prep(const float* __restrict__ queries, const unsigned* __restrict__ scale_bits,
                       float* __restrict__ rscale, float* __restrict__ qs,
                       float* __restrict__ qnorm) {
  __shared__ float rs[DD];
  int t = threadIdx.x;
  if (t < DD) {
    float s = __uint_as_float(scale_bits[t]);
    float r = (s == 0.f) ? 0.f : 1.f / s;
    rs[t] = r;
    rscale[t] = r;
  }
  __syncthreads();
  float nrm = 0.f;
  #pragma unroll
  for (int d = 0; d < DD; ++d) {
    float v = queries[t*DD + d] * rs[d];
    qs[t*DD + d] = v;
    nrm = fmaf(v, v, nrm);
  }
  qnorm[t] = nrm;
}

// K3: per-block partial top-3 per query.  Each thread owns queries t and t+256
// (top-3 state in registers).  Feature chunk staged in LDS as [FC][28]
// (27 scaled dims + fnorm); q[27] = -0.5 makes the inner loop a pure 28-FMA dot:
//   acc = sum_d f_d*q_d - 0.5*||f||^2 ;  d2 = -2*acc + qnorm  (qnorm added at merge)
// Top-3 smallest d2 == top-3 largest acc.
__global__ __launch_bounds__(NTHR) void k_knn(
    const float* __restrict__ feats, const float* __restrict__ rscale,
    const float* __restrict__ qs, float* __restrict__ pd2, int* __restrict__ pidx,
    int nchunks, int nblk, int nfeat) {
  __shared__ float lds[FC*28];
  int t = threadIdx.x;
  float q0[28], q1[28];
  #pragma unroll
  for (int d = 0; d < DD; ++d) {
    q0[d] = qs[t*DD + d];
    q1[d] = qs[(t+NTHR)*DD + d];
  }
  q0[27] = -0.5f; q1[27] = -0.5f;
  float s00=-INFINITY, s01=-INFINITY, s02=-INFINITY;
  float s10=-INFINITY, s11=-INFINITY, s12=-INFINITY;
  int   i00=0x7fffffff, i01=0x7fffffff, i02=0x7fffffff;
  int   i10=0x7fffffff, i11=0x7fffffff, i12=0x7fffffff;
  int ntot = nfeat * DD;

  for (int c = blockIdx.x; c < nchunks; c += nblk) {
    __syncthreads();
    int base = c * FCD;
    #pragma unroll
    for (int j = 0; j < 14; ++j) {
      int i = t + j*NTHR;
      if (i < FCD) {
        int f = i / DD;
        int d = i - f*DD;
        int gi = base + i;
        float v = (gi < ntot) ? feats[gi] * rscale[d] : 0.f;
        lds[f*28 + d] = v;
      }
    }
    __syncthreads();
    if (t < FC) {
      float sm = 0.f;
      #pragma unroll
      for (int d = 0; d < DD; ++d) { float v = lds[t*28 + d]; sm = fmaf(v, v, sm); }
      int fg = c*FC + t;
      lds[t*28 + 27] = (fg < nfeat) ? sm : INFINITY;   // pad rows: acc -> -inf
    }
    __syncthreads();
    const float4* lf = (const float4*)lds;
    #pragma unroll 2
    for (int f = 0; f < FC; ++f) {
      float a0a=0.f, a0b=0.f, a1a=0.f, a1b=0.f;
      #pragma unroll
      for (int j = 0; j < 7; ++j) {
        float4 v = lf[f*7 + j];   // uniform address -> LDS broadcast, conflict-free
        if ((j & 1) == 0) {
          a0a = fmaf(v.x, q0[4*j+0], a0a);
          a0a = fmaf(v.y, q0[4*j+1], a0a);
          a0a = fmaf(v.z, q0[4*j+2], a0a);
          a0a = fmaf(v.w, q0[4*j+3], a0a);
          a1a = fmaf(v.x, q1[4*j+0], a1a);
          a1a = fmaf(v.y, q1[4*j+1], a1a);
          a1a = fmaf(v.z, q1[4*j+2], a1a);
          a1a = fmaf(v.w, q1[4*j+3], a1a);
        } else {
          a0b = fmaf(v.x, q0[4*j+0], a0b);
          a0b = fmaf(v.y, q0[4*j+1], a0b);
          a0b = fmaf(v.z, q0[4*j+2], a0b);
          a0b = fmaf(v.w, q0[4*j+3], a0b);
          a1b = fmaf(v.x, q1[4*j+0], a1b);
          a1b = fmaf(v.y, q1[4*j+1], a1b);
          a1b = fmaf(v.z, q1[4*j+2], a1b);
          a1b = fmaf(v.w, q1[4*j+3], a1b);
        }
      }
      float acc0 = a0a + a0b;
      float acc1 = a1a + a1b;
      int fi = c*FC + f;
      if (acc0 > s02) {          // strict > : ties keep earlier (smaller) index
        if (acc0 > s00)      { s02=s01;i02=i01; s01=s00;i01=i00; s00=acc0;i00=fi; }
        else if (acc0 > s01) { s02=s01;i02=i01; s01=acc0;i01=fi; }
        else                 { s02=acc0; i02=fi; }
      }
      if (acc1 > s12) {
        if (acc1 > s10)      { s12=s11;i12=i11; s11=s10;i11=i10; s10=acc1;i10=fi; }
        else if (acc1 > s11) { s12=s11;i12=i11; s11=acc1;i11=fi; }
        else                 { s12=acc1; i12=fi; }
      }
    }
  }
  // write partials: layout [q][blk][k], key = -2*acc (== d2 - qnorm)
  long off0 = ((long)t * nblk + blockIdx.x) * 3;
  pd2[off0+0] = -2.f*s00; pd2[off0+1] = -2.f*s01; pd2[off0+2] = -2.f*s02;
  pidx[off0+0] = i00;     pidx[off0+1] = i01;     pidx[off0+2] = i02;
  long off1 = ((long)(t+NTHR) * nblk + blockIdx.x) * 3;
  pd2[off1+0] = -2.f*s10; pd2[off1+1] = -2.f*s11; pd2[off1+2] = -2.f*s12;
  pidx[off1+0] = i10;     pidx[off1+1] = i11;     pidx[off1+2] = i12;
}

// insert (vv,ii) into sorted (c0<=c1<=c2), tie-break by smaller index (lax.top_k stability)
#define INS(vv, ii) do { \
  if ((vv) < c2 || ((vv) == c2 && (ii) < j2)) { \
    if ((vv) < c0 || ((vv) == c0 && (ii) < j0))      { c2=c1;j2=j1; c1=c0;j1=j0; c0=(vv);j0=(ii); } \
    else if ((vv) < c1 || ((vv) == c1 && (ii) < j1)) { c2=c1;j2=j1; c1=(vv);j1=(ii); } \
    else                                             { c2=(vv); j2=(ii); } \
  } \
} while (0)

// K4: one block per query — merge nblk*3 candidates, then epilogue (sqrt, vote, zero-hit).
__global__ __launch_bounds__(NTHR) void k_merge(
    const float* __restrict__ pd2, const int* __restrict__ pidx,
    const float* __restrict__ qnorm, const float* __restrict__ labels,
    float* __restrict__ out, int nblk) {
  __shared__ float sk[NTHR*3];
  __shared__ int   si[NTHR*3];
  int q = blockIdx.x, t = threadIdx.x;
  float c0=INFINITY, c1=INFINITY, c2=INFINITY;
  int   j0=0x7fffffff, j1=0x7fffffff, j2=0x7fffffff;
  int ncand = nblk * 3;
  const float* pq = pd2  + (long)q * nblk * 3;
  const int*   iq = pidx + (long)q * nblk * 3;
  for (int i = t; i < ncand; i += NTHR) {
    float v = pq[i]; int ix = iq[i];
    INS(v, ix);
  }
  sk[t*3+0]=c0; sk[t*3+1]=c1; sk[t*3+2]=c2;
  si[t*3+0]=j0; si[t*3+1]=j1; si[t*3+2]=j2;
  __syncthreads();
  if (t < 64) {
    for (int s = 1; s < 4; ++s) {
      int b = t + s*64;
      #pragma unroll
      for (int k = 0; k < 3; ++k) { float v = sk[b*3+k]; int ix = si[b*3+k]; INS(v, ix); }
    }
    sk[t*3+0]=c0; sk[t*3+1]=c1; sk[t*3+2]=c2;
    si[t*3+0]=j0; si[t*3+1]=j1; si[t*3+2]=j2;
  }
  __syncthreads();
  if (t == 0) {
    for (int s = 1; s < 64; ++s) {
      #pragma unroll
      for (int k = 0; k < 3; ++k) { float v = sk[s*3+k]; int ix = si[s*3+k]; INS(v, ix); }
    }
    float qn = qnorm[q];
    float kd0 = sqrtf(fmaxf(c0 + qn, 0.f));
    float kd1 = sqrtf(fmaxf(c1 + qn, 0.f));
    float kd2 = sqrtf(fmaxf(c2 + qn, 0.f));
    const float* l0 = labels + (long)j0 * NC;
    const float* l1 = labels + (long)j1 * NC;
    const float* l2 = labels + (long)j2 * NC;
    float inv0 = 1.f / ((kd0 == 0.f) ? 1.f : kd0);
    float inv1 = 1.f / ((kd1 == 0.f) ? 1.f : kd1);
    float inv2 = 1.f / ((kd2 == 0.f) ? 1.f : kd2);
    float w[NC];
    #pragma unroll
    for (int cc = 0; cc < NC; ++cc)
      w[cc] = l0[cc]*inv0 + l1[cc]*inv1 + l2[cc]*inv2;
    int am = 0; float bw = w[0];
    #pragma unroll
    for (int cc = 1; cc < NC; ++cc) if (w[cc] > bw) { bw = w[cc]; am = cc; }
    float* o = out + q * (KK + NC);
    o[0] = kd0; o[1] = kd1; o[2] = kd2;
    if (kd0 == 0.f) {
      #pragma unroll
      for (int cc = 0; cc < NC; ++cc) o[3+cc] = l0[cc];
    } else {
      #pragma unroll
      for (int cc = 0; cc < NC; ++cc) o[3+cc] = (cc == am) ? 1.f : 0.f;
    }
  }
}

extern "C" void kernel_launch(void* const* d_in, const int* in_sizes, int n_in,
                              void* d_out, int out_size, void* d_ws, size_t ws_size,
                              hipStream_t stream) {
  const float* queries = (const float*)d_in[0];   // (512, 27)
  const float* feats   = (const float*)d_in[1];   // (200000, 27)
  const float* labels  = (const float*)d_in[2];   // (200000, 10)
  float* out = (float*)d_out;                     // (512, 13)
  char*  ws  = (char*)d_ws;

  int total = in_sizes[1];            // 5,400,000
  int nfeat = total / DD;             // 200,000
  unsigned* scale_bits = (unsigned*)ws;            // 27 u32 @ 0
  float* rscale = (float*)(ws + 128);              // 27 f32
  float* qnorm  = (float*)(ws + 256);              // 512 f32
  float* qs     = (float*)(ws + 2304);             // 512*27 f32
  float* pd2    = (float*)(ws + 65536);            // [512][nblk][3] f32

  int nchunks = (nfeat + FC - 1) / FC;             // 1563
  long cap = (ws_size > 65536) ? (long)((ws_size - 65536) / ((long)NQ*3*8)) : 1;
  int nblk = (int)((cap < (long)nchunks) ? cap : (long)nchunks);
  if (nblk < 1) nblk = 1;
  int* pidx = (int*)(ws + 65536 + (long)nblk * NQ * 3 * 4);

  hipMemsetAsync(ws, 0, 128, stream);              // zero scale_bits
  k_scale<<<432, 256, 0, stream>>>(feats, scale_bits, total, total / 4);
  k_prep <<<1, NQ, 0, stream>>>(queries, scale_bits, rscale, qs, qnorm);
  k_knn  <<<nblk, NTHR, 0, stream>>>(feats, rscale, qs, pd2, pidx, nchunks, nblk, nfeat);
  k_merge<<<NQ, NTHR, 0, stream>>>(pd2, pidx, qnorm, labels, out, nblk);
}